// Round 2
// baseline (1217.387 us; speedup 1.0000x reference)
//
#include <hip/hip_runtime.h>
#include <math.h>

// B=64, I=K=2048, H=N=2048, T=128.  m = b*128 + t (M=8192).
// Numerics contract (VALIDATED GREEN): Eigen gebp kc=320 K-panels; per C
// element an ascending-k FMA chain within each 320-panel (register
// accumulator), panels combined by UNFUSED f32 adds (beta=0 first).
// w_eff = __fmul_rn(weight, strength) rounded once. Scan: f32 state,
// unfused mul/add; exact batch mean via ballot/popcount; correctly-rounded
// expf via (float)exp((double)quotient).
//
// R2: wave-level A-broadcast GEMM. Each wave owns 16 m-rows x 256 h-cols.
// A values (16 per k) live in a tiny per-wave LDS block read via
// same-address broadcast (conflict-free); B is one ds_read_b128/lane/k.
// LDS traffic drops 4x to 0.25 B/FMA -> VALU(FMA)-bound. Per-element FMA
// chain order is bit-identical to the green kernel (same ascending-k chain,
// same kc=320 unfused panel folds). Ct layout flips to [M][Hc] so the
// wave's stores are coalesced; scan staging updated to match.

#define KT 32
#define HT 256

__device__ __forceinline__ void async_copy16(const float* g, float* l) {
    __builtin_amdgcn_global_load_lds(
        (const __attribute__((address_space(1))) void*)g,
        (__attribute__((address_space(3))) void*)l, 16, 0, 0);
}

// weff[i][hl] = __fmul_rn(weight[i][h_base+hl], strength[i][h_base+hl])
__global__ __launch_bounds__(256) void weff_kernel(
    const float* __restrict__ weight, const float* __restrict__ strength,
    float* __restrict__ weff, int h_base, int Hc)
{
    const int i = blockIdx.x;  // input row 0..2047
    const float* wr = weight   + (size_t)i * 2048 + h_base;
    const float* sr = strength + (size_t)i * 2048 + h_base;
    float* dr = weff + (size_t)i * Hc;
    for (int c = threadIdx.x * 4; c < Hc; c += 1024) {
        float4 wv = *(const float4*)&wr[c];
        float4 sv = *(const float4*)&sr[c];
        float4 o;
        o.x = __fmul_rn(wv.x, sv.x);
        o.y = __fmul_rn(wv.y, sv.y);
        o.z = __fmul_rn(wv.z, sv.z);
        o.w = __fmul_rn(wv.w, sv.w);
        *(float4*)&dr[c] = o;
    }
}

__global__ __launch_bounds__(256, 2) void gemm_kernel(
    const float* __restrict__ spikes,  // [64][2048][128]
    const float* __restrict__ weff,    // [2048][Hc]
    float* __restrict__ Ct,            // [M=8192][Hc]
    int Hc)
{
    __shared__ __align__(16) float Bt[2][KT][HT];      // 64 KiB
    __shared__ __align__(16) float At[2][4][KT][16];   // 16 KiB

    const int tid  = threadIdx.x;
    const int w    = tid >> 6;             // wave 0..3
    const int lane = tid & 63;
    const int bx   = blockIdx.x;           // h-tile within chunk
    const int by   = blockIdx.y;           // m-block (64 m)
    const int h0   = bx * HT;

    const int mg   = by * 4 + w;           // global m-group of 16 (0..511)
    const int b    = mg >> 3;              // batch index
    const int t0   = (mg & 7) << 4;        // time offset within batch

    float acc[16][4];   // current 320-panel accumulator (ascending-k chain)
    float tot[16][4];   // running unfused panel total
#pragma unroll
    for (int i = 0; i < 16; i++)
#pragma unroll
        for (int j = 0; j < 4; j++) { acc[i][j] = 0.0f; tot[i][j] = 0.0f; }

    // A source: spikes[b][k][t0 + 0..15] (16 consecutive floats per k)
    const float* a_base = spikes + (size_t)b * 262144 + t0;
    const int arow = lane >> 2;            // 0..15 (k-row within 16-row group)
    const int acol = lane & 3;             // 16-B chunk within the 64-B row

    // Stage tile kt into buffer buf. LDS dest is wave-uniform (HW adds
    // lane*16); global src is per-lane. B: 8 rows of 1 KiB per wave.
    // A: wave's own [32][16] block as 2x 1-KiB DMA (strided global rows).
    auto stage = [&](int buf, int kt) {
        const int k0 = kt * KT;
#pragma unroll
        for (int j = 0; j < 8; j++) {
            const int r = (w << 3) + j;
            async_copy16(&weff[(size_t)(k0 + r) * Hc + h0 + (lane << 2)],
                         &Bt[buf][r][0]);
        }
#pragma unroll
        for (int i = 0; i < 2; i++) {
            const int r = (i << 4) + arow;
            async_copy16(&a_base[(size_t)(k0 + r) * 128 + (acol << 2)],
                         &At[buf][w][i << 4][0]);
        }
    };

    stage(0, 0);
    __syncthreads();   // prologue drain (only exposed DMA latency)

    int cur = 0;
    for (int kt = 0; kt < 64; kt++) {
        if (kt < 63) stage(cur ^ 1, kt + 1);   // issue DMA, no wait

        // 32 k-steps; per k: 1 B-read (lane-strided b128) + 4 A-broadcast
        // reads (same addr across lanes) + 64 v_fmac. Offsets are
        // compile-time immediates -> no address VALU in steady state.
#pragma unroll
        for (int k = 0; k < KT; k++) {
            const float4 bv = *(const float4*)&Bt[cur][k][lane << 2];
            const float4 a0 = *(const float4*)&At[cur][w][k][0];
            const float4 a1 = *(const float4*)&At[cur][w][k][4];
            const float4 a2 = *(const float4*)&At[cur][w][k][8];
            const float4 a3 = *(const float4*)&At[cur][w][k][12];
#define FMA4(mi, av) \
            acc[mi][0] = __builtin_fmaf(av, bv.x, acc[mi][0]); \
            acc[mi][1] = __builtin_fmaf(av, bv.y, acc[mi][1]); \
            acc[mi][2] = __builtin_fmaf(av, bv.z, acc[mi][2]); \
            acc[mi][3] = __builtin_fmaf(av, bv.w, acc[mi][3]);
            FMA4(0,  a0.x) FMA4(1,  a0.y) FMA4(2,  a0.z) FMA4(3,  a0.w)
            FMA4(4,  a1.x) FMA4(5,  a1.y) FMA4(6,  a1.z) FMA4(7,  a1.w)
            FMA4(8,  a2.x) FMA4(9,  a2.y) FMA4(10, a2.z) FMA4(11, a2.w)
            FMA4(12, a3.x) FMA4(13, a3.y) FMA4(14, a3.z) FMA4(15, a3.w)
#undef FMA4
        }

        // Eigen kc=320 panel boundary: unfused fold into total, reset chain
        if (((kt + 1) % 10 == 0) || (kt == 63)) {
#pragma unroll
            for (int i = 0; i < 16; i++)
#pragma unroll
                for (int j = 0; j < 4; j++) {
                    tot[i][j] = __fadd_rn(tot[i][j], acc[i][j]);
                    acc[i][j] = 0.0f;
                }
        }

        __syncthreads();   // implicit vmcnt(0) drain: DMA had full compute
        cur ^= 1;          // phase to land; also fences buffer reuse
    }

    // Coalesced stores: per m, 64 lanes x 16 B = 1 KiB contiguous.
    const size_t mbase = (size_t)by * 64 + (size_t)w * 16;
#pragma unroll
    for (int i = 0; i < 16; i++) {
        *(float4*)&Ct[(mbase + i) * Hc + h0 + (lane << 2)] =
            make_float4(tot[i][0], tot[i][1], tot[i][2], tot[i][3]);
    }
}

// One wave (64 lanes) per h; lane = batch b. Scan state f32, unfused.
// Batch-mean via ballot/popcount (exact). Validated numerics — UNCHANGED.
// Staging updated for Wt layout [M][Hc] (16-B scattered L2/L3 reads).
__global__ __launch_bounds__(256) void scan_kernel(
    const float* __restrict__ Wt,          // [M=8192][Hc] f32 chunk-local
    const float* __restrict__ threshold,   // [H] f32 global
    const float* __restrict__ p_tau_mem,
    const float* __restrict__ p_tau_syn,
    const float* __restrict__ p_target,
    const float* __restrict__ p_lr,
    float* __restrict__ out,               // [B][H][T] f32 global
    int h_base, int Hc)
{
    __shared__ float S[4 * 64 * 17];
    __shared__ unsigned int Bits[4][64][4];

    const int tid  = threadIdx.x;
    const int w    = tid >> 6;
    const int lane = tid & 63;            // batch b
    const int hl   = blockIdx.x * 4 + w;  // chunk-local h
    const int h0   = blockIdx.x * 4;

    const float tau_mem = p_tau_mem[0];
    const float tau_syn = p_tau_syn[0];
    const float target  = p_target[0];
    const float lr      = p_lr[0];
    const float a_mem = (float)exp((double)__fdiv_rn(-0.001f, tau_mem));
    const float a_syn = (float)exp((double)__fdiv_rn(-0.001f, tau_syn));

    float i_syn = 0.0f, v_mem = 0.0f;
    float thr = threshold[h_base + hl];
    float fre = 0.0f;
    unsigned int bits[4] = {0u, 0u, 0u, 0u};

    for (int tc = 0; tc < 128; tc += 16) {
        __syncthreads();
        // Stage [4 h][64 b][16 t] from Wt[M][Hc]: one float4 (h0..h0+3)
        // per (b, t) pair, transposed into S's h-planes.
#pragma unroll
        for (int i = 0; i < 4; i++) {
            const int idx = tid + 256 * i;     // 0..1023
            const int bb  = idx >> 4;          // batch 0..63
            const int tw  = idx & 15;          // t within chunk
            float4 v = *(const float4*)&Wt[(size_t)(bb * 128 + tc + tw) * Hc + h0];
            S[(0 * 64 + bb) * 17 + tw] = v.x;
            S[(1 * 64 + bb) * 17 + tw] = v.y;
            S[(2 * 64 + bb) * 17 + tw] = v.z;
            S[(3 * 64 + bb) * 17 + tw] = v.w;
        }
        __syncthreads();

        const float* row = &S[(w * 64 + lane) * 17];
#pragma unroll
        for (int tt = 0; tt < 16; tt++) {
            const int t = tc + tt;
            const float wv = row[tt];
            i_syn = __fadd_rn(__fmul_rn(a_syn, i_syn), wv);
            v_mem = __fadd_rn(__fmul_rn(a_mem, v_mem), i_syn);
            const bool sp = (v_mem >= thr);
            const unsigned long long mask = __ballot(sp);
            if (sp) v_mem = __fsub_rn(v_mem, thr);
            const int cnt = __popcll(mask);
            const float rate = __fmul_rn((float)cnt, 0.015625f);
            fre = __fadd_rn(__fmul_rn(0.99f, fre), __fmul_rn(0.01f, rate));
            thr = __fadd_rn(thr, __fmul_rn(lr, __fsub_rn(fre, target)));
            if (sp) bits[t >> 5] |= (1u << (t & 31));
        }
    }

    __syncthreads();
    Bits[w][lane][0] = bits[0];
    Bits[w][lane][1] = bits[1];
    Bits[w][lane][2] = bits[2];
    Bits[w][lane][3] = bits[3];
    __syncthreads();

    for (int b = 0; b < 64; b++) {
        const unsigned int word = Bits[w][b][lane >> 4];
        float2 v;
        v.x = ((word >> ((2 * lane) & 31)) & 1u) ? 1.0f : 0.0f;
        v.y = ((word >> ((2 * lane + 1) & 31)) & 1u) ? 1.0f : 0.0f;
        *(float2*)&out[((size_t)b * 2048 + h_base + hl) * 128 + 2 * lane] = v;
    }
}

extern "C" void kernel_launch(void* const* d_in, const int* in_sizes, int n_in,
                              void* d_out, int out_size, void* d_ws, size_t ws_size,
                              hipStream_t stream) {
    const float* spikes    = (const float*)d_in[0];
    const float* weight    = (const float*)d_in[1];
    const float* strength  = (const float*)d_in[2];
    const float* threshold = (const float*)d_in[3];
    const float* tau_mem   = (const float*)d_in[4];
    const float* tau_syn   = (const float*)d_in[5];
    const float* target    = (const float*)d_in[6];
    const float* lr        = (const float*)d_in[7];

    float* out = (float*)d_out;

    // ws holds Wt [8192][Hc] f32 + weff [2048][Hc] f32 = Hc*40960 bytes.
    int Hc = 2048;
    while (Hc > 256 && (size_t)Hc * 40960ull > ws_size) Hc >>= 1;

    float* Wt   = (float*)d_ws;
    float* weff = (float*)d_ws + (size_t)Hc * 8192;

    for (int hb = 0; hb < 2048; hb += Hc) {
        weff_kernel<<<2048, 256, 0, stream>>>(weight, strength, weff, hb, Hc);
        gemm_kernel<<<dim3(Hc / HT, 128), 256, 0, stream>>>(spikes, weff, Wt, Hc);
        scan_kernel<<<Hc / 4, 256, 0, stream>>>(
            Wt, threshold, tau_mem, tau_syn, target, lr, out, hb, Hc);
    }
}

// Round 4
// 1171.585 us; speedup vs baseline: 1.0391x; 1.0391x over previous
//
#include <hip/hip_runtime.h>
#include <math.h>

// B=64, I=K=2048, H=N=2048, T=128.  m = b*128 + t (M=8192).
// Numerics contract (VALIDATED GREEN): Eigen gebp kc=320 K-panels; per C
// element an ascending-k FMA chain within each 320-panel (register
// accumulator), panels combined by UNFUSED f32 adds (beta=0 first).
// w_eff = __fmul_rn(weight, strength) rounded once. Scan: f32 state,
// unfused mul/add; exact batch mean via ballot/popcount; correctly-rounded
// expf via (float)exp((double)quotient).
//
// R4 = R3 resubmitted verbatim (R3 bench died to container infra, no GPU
// data). Design: R1's global layouts (FETCH 292 MB / WRITE 65 MB) with a
// wave-broadcast compute map: wave owns 32 m x 128 h; A via 8 wave-uniform
// ds_read_b128 broadcasts per k (free), B via one ds_read_b64 per lane.
// LDS traffic 1.0 -> 0.15 B/FMA => VALU(FMA)-bound. FMA chain order
// bit-identical (ascending-k chain per (m,h), kc=320 unfused folds).

#define KT 32

__device__ __forceinline__ void async_copy16(const float* g, float* l) {
    __builtin_amdgcn_global_load_lds(
        (const __attribute__((address_space(1))) void*)g,
        (__attribute__((address_space(3))) void*)l, 16, 0, 0);
}

// weff[i][hl] = __fmul_rn(weight[i][h_base+hl], strength[i][h_base+hl])
__global__ __launch_bounds__(256) void weff_kernel(
    const float* __restrict__ weight, const float* __restrict__ strength,
    float* __restrict__ weff, int h_base, int Hc)
{
    const int i = blockIdx.x;  // input row 0..2047
    const float* wr = weight   + (size_t)i * 2048 + h_base;
    const float* sr = strength + (size_t)i * 2048 + h_base;
    float* dr = weff + (size_t)i * Hc;
    for (int c = threadIdx.x * 4; c < Hc; c += 1024) {
        float4 wv = *(const float4*)&wr[c];
        float4 sv = *(const float4*)&sr[c];
        float4 o;
        o.x = __fmul_rn(wv.x, sv.x);
        o.y = __fmul_rn(wv.y, sv.y);
        o.z = __fmul_rn(wv.z, sv.z);
        o.w = __fmul_rn(wv.w, sv.w);
        *(float4*)&dr[c] = o;
    }
}

__global__ __launch_bounds__(256, 2) void gemm_kernel(
    const float* __restrict__ spikes,  // [64][2048][128]
    const float* __restrict__ weff,    // [2048][Hc]
    float* __restrict__ Ct,            // [Hc][M=8192]
    int Hc)
{
    __shared__ __align__(16) float A_lds[2][KT][128];  // 32 KiB, linear
    __shared__ __align__(16) float W_lds[2][KT][128];  // 32 KiB, linear

    const int tid  = threadIdx.x;
    const int w    = tid >> 6;         // wave 0..3 -> m-group w*32..w*32+31
    const int lane = tid & 63;         // lane -> h pair (2*lane, 2*lane+1)
    const int bx   = blockIdx.x;       // h-tile within chunk
    const int by   = blockIdx.y;       // batch b
    const int h0l  = bx * 128;
    const int m0   = by * 128;

    float acc[32][2];   // current 320-panel accumulator (ascending-k chain)
    float tot[32][2];   // running unfused panel total
#pragma unroll
    for (int i = 0; i < 32; i++) {
        acc[i][0] = 0.0f; acc[i][1] = 0.0f;
        tot[i][0] = 0.0f; tot[i][1] = 0.0f;
    }

    const float* a_base = spikes + (size_t)by * 262144;  // b * I * T

    // Stage tile kt into buffer buf (R1's proven DMA pattern).
    // A tile = rows k0..k0+31 x 128 t = 16 KiB CONTIGUOUS global; wave w
    // covers its 4-KiB quarter with 4 instrs. W tile = 32 rows of 512 B
    // (global stride Hc); 2 rows per instr (lanes 0-31 row r, 32-63 r+1).
    auto stage = [&](int buf, int kt) {
        const int k0 = kt * KT;
        const float* asrc = a_base + ((size_t)k0 << 7) + (w << 10) + (lane << 2);
        float* adst = &A_lds[buf][0][0] + (w << 10);
#pragma unroll
        for (int i = 0; i < 4; i++)
            async_copy16(asrc + (i << 8), adst + (i << 8));

        const float* wsrc = &weff[(size_t)(k0 + (w << 3) + (lane >> 5)) * Hc
                                  + h0l + ((lane & 31) << 2)];
        float* wdst = &W_lds[buf][w << 3][0];
#pragma unroll
        for (int j = 0; j < 4; j++)
            async_copy16(wsrc + (size_t)(2 * j) * Hc, wdst + (j << 8));
    };

    stage(0, 0);
    __syncthreads();   // prologue drain (only exposed DMA latency)

    int cur = 0;
    for (int kt = 0; kt < 64; kt++) {
        if (kt < 63) stage(cur ^ 1, kt + 1);   // issue DMA, no wait

        // Per k: 8 wave-uniform b128 broadcasts (A, free) + 1 b64 (B,
        // 512 B spread) + 64 v_fmac. All LDS offsets are compile-time
        // immediates off per-buffer bases.
#pragma unroll
        for (int k = 0; k < KT; k++) {
            const float4 a0 = *(const float4*)&A_lds[cur][k][(w << 5) + 0];
            const float4 a1 = *(const float4*)&A_lds[cur][k][(w << 5) + 4];
            const float4 a2 = *(const float4*)&A_lds[cur][k][(w << 5) + 8];
            const float4 a3 = *(const float4*)&A_lds[cur][k][(w << 5) + 12];
            const float4 a4 = *(const float4*)&A_lds[cur][k][(w << 5) + 16];
            const float4 a5 = *(const float4*)&A_lds[cur][k][(w << 5) + 20];
            const float4 a6 = *(const float4*)&A_lds[cur][k][(w << 5) + 24];
            const float4 a7 = *(const float4*)&A_lds[cur][k][(w << 5) + 28];
            const float2 bv = *(const float2*)&W_lds[cur][k][lane << 1];
#define FMA2(mi, av) \
            acc[mi][0] = __builtin_fmaf(av, bv.x, acc[mi][0]); \
            acc[mi][1] = __builtin_fmaf(av, bv.y, acc[mi][1]);
            FMA2(0,  a0.x) FMA2(1,  a0.y) FMA2(2,  a0.z) FMA2(3,  a0.w)
            FMA2(4,  a1.x) FMA2(5,  a1.y) FMA2(6,  a1.z) FMA2(7,  a1.w)
            FMA2(8,  a2.x) FMA2(9,  a2.y) FMA2(10, a2.z) FMA2(11, a2.w)
            FMA2(12, a3.x) FMA2(13, a3.y) FMA2(14, a3.z) FMA2(15, a3.w)
            FMA2(16, a4.x) FMA2(17, a4.y) FMA2(18, a4.z) FMA2(19, a4.w)
            FMA2(20, a5.x) FMA2(21, a5.y) FMA2(22, a5.z) FMA2(23, a5.w)
            FMA2(24, a6.x) FMA2(25, a6.y) FMA2(26, a6.z) FMA2(27, a6.w)
            FMA2(28, a7.x) FMA2(29, a7.y) FMA2(30, a7.z) FMA2(31, a7.w)
#undef FMA2
        }

        // Eigen kc=320 panel boundary: unfused fold into total, reset chain
        if (((kt + 1) % 10 == 0) || (kt == 63)) {
#pragma unroll
            for (int i = 0; i < 32; i++) {
                tot[i][0] = __fadd_rn(tot[i][0], acc[i][0]); acc[i][0] = 0.0f;
                tot[i][1] = __fadd_rn(tot[i][1], acc[i][1]); acc[i][1] = 0.0f;
            }
        }

        __syncthreads();   // implicit vmcnt(0) drain: DMA had full compute
        cur ^= 1;          // phase to land; also fences buffer reuse
    }

    // Store: lane owns h-rows 2*lane, 2*lane+1; 32 contiguous m each.
    // 16-B per-lane scatters; L2 merges 8 consecutive 16-B into full lines.
    const size_t mg = (size_t)m0 + (w << 5);
#pragma unroll
    for (int d = 0; d < 2; d++) {
        float* crow = &Ct[(size_t)(h0l + (lane << 1) + d) * 8192 + mg];
#pragma unroll
        for (int q = 0; q < 8; q++) {
            *(float4*)&crow[q << 2] = make_float4(
                tot[4 * q][d], tot[4 * q + 1][d],
                tot[4 * q + 2][d], tot[4 * q + 3][d]);
        }
    }
}

// One wave (64 lanes) per h; lane = batch b. Scan state f32, unfused.
// Batch-mean via ballot/popcount (exact). Validated numerics — UNCHANGED
// (verbatim R1 version; Wt layout [Hc][B][T] = [Hc][8192]).
__global__ __launch_bounds__(256) void scan_kernel(
    const float* __restrict__ Wt,          // [Hc][B][T] f32 chunk-local
    const float* __restrict__ threshold,   // [H] f32 global
    const float* __restrict__ p_tau_mem,
    const float* __restrict__ p_tau_syn,
    const float* __restrict__ p_target,
    const float* __restrict__ p_lr,
    float* __restrict__ out,               // [B][H][T] f32 global
    int h_base)
{
    __shared__ float S[4 * 64 * 17];
    __shared__ unsigned int Bits[4][64][4];

    const int tid  = threadIdx.x;
    const int w    = tid >> 6;
    const int lane = tid & 63;            // batch b
    const int hl   = blockIdx.x * 4 + w;  // chunk-local h

    const float tau_mem = p_tau_mem[0];
    const float tau_syn = p_tau_syn[0];
    const float target  = p_target[0];
    const float lr      = p_lr[0];
    const float a_mem = (float)exp((double)__fdiv_rn(-0.001f, tau_mem));
    const float a_syn = (float)exp((double)__fdiv_rn(-0.001f, tau_syn));

    float i_syn = 0.0f, v_mem = 0.0f;
    float thr = threshold[h_base + hl];
    float fre = 0.0f;
    unsigned int bits[4] = {0u, 0u, 0u, 0u};

    const int st4 = tid & 3;
    const int sb  = (tid >> 2) & 63;

    for (int tc = 0; tc < 128; tc += 16) {
        __syncthreads();
#pragma unroll
        for (int hh = 0; hh < 4; hh++) {
            const int hg = blockIdx.x * 4 + hh;
            float4 v = *(const float4*)&Wt[(size_t)hg * 8192 + sb * 128 + tc + 4 * st4];
            float* row = &S[(hh * 64 + sb) * 17];
            row[4 * st4 + 0] = v.x;
            row[4 * st4 + 1] = v.y;
            row[4 * st4 + 2] = v.z;
            row[4 * st4 + 3] = v.w;
        }
        __syncthreads();

        const float* row = &S[(w * 64 + lane) * 17];
#pragma unroll
        for (int tt = 0; tt < 16; tt++) {
            const int t = tc + tt;
            const float wv = row[tt];
            i_syn = __fadd_rn(__fmul_rn(a_syn, i_syn), wv);
            v_mem = __fadd_rn(__fmul_rn(a_mem, v_mem), i_syn);
            const bool sp = (v_mem >= thr);
            const unsigned long long mask = __ballot(sp);
            if (sp) v_mem = __fsub_rn(v_mem, thr);
            const int cnt = __popcll(mask);
            const float rate = __fmul_rn((float)cnt, 0.015625f);
            fre = __fadd_rn(__fmul_rn(0.99f, fre), __fmul_rn(0.01f, rate));
            thr = __fadd_rn(thr, __fmul_rn(lr, __fsub_rn(fre, target)));
            if (sp) bits[t >> 5] |= (1u << (t & 31));
        }
    }

    __syncthreads();
    Bits[w][lane][0] = bits[0];
    Bits[w][lane][1] = bits[1];
    Bits[w][lane][2] = bits[2];
    Bits[w][lane][3] = bits[3];
    __syncthreads();

    for (int b = 0; b < 64; b++) {
        const unsigned int word = Bits[w][b][lane >> 4];
        float2 v;
        v.x = ((word >> ((2 * lane) & 31)) & 1u) ? 1.0f : 0.0f;
        v.y = ((word >> ((2 * lane + 1) & 31)) & 1u) ? 1.0f : 0.0f;
        *(float2*)&out[((size_t)b * 2048 + h_base + hl) * 128 + 2 * lane] = v;
    }
}

extern "C" void kernel_launch(void* const* d_in, const int* in_sizes, int n_in,
                              void* d_out, int out_size, void* d_ws, size_t ws_size,
                              hipStream_t stream) {
    const float* spikes    = (const float*)d_in[0];
    const float* weight    = (const float*)d_in[1];
    const float* strength  = (const float*)d_in[2];
    const float* threshold = (const float*)d_in[3];
    const float* tau_mem   = (const float*)d_in[4];
    const float* tau_syn   = (const float*)d_in[5];
    const float* target    = (const float*)d_in[6];
    const float* lr        = (const float*)d_in[7];

    float* out = (float*)d_out;

    // ws holds Wt [Hc][8192] f32 + weff [2048][Hc] f32 = Hc*40960 bytes.
    int Hc = 2048;
    while (Hc > 128 && (size_t)Hc * 40960ull > ws_size) Hc >>= 1;

    float* Wt   = (float*)d_ws;
    float* weff = (float*)d_ws + (size_t)Hc * 8192;

    for (int hb = 0; hb < 2048; hb += Hc) {
        weff_kernel<<<2048, 256, 0, stream>>>(weight, strength, weff, hb, Hc);
        gemm_kernel<<<dim3(Hc / 128, 64), 256, 0, stream>>>(spikes, weff, Wt, Hc);
        scan_kernel<<<Hc / 4, 256, 0, stream>>>(
            Wt, threshold, tau_mem, tau_syn, target, lr, out, hb);
    }
}

// Round 5
// 1105.706 us; speedup vs baseline: 1.1010x; 1.0596x over previous
//
#include <hip/hip_runtime.h>
#include <math.h>

// B=64, I=K=2048, H=N=2048, T=128.  m = b*128 + t (M=8192).
// Numerics contract (VALIDATED GREEN): Eigen gebp kc=320 K-panels; per C
// element an ascending-k FMA chain within each 320-panel (register
// accumulator), panels combined by UNFUSED f32 adds (beta=0 first).
// w_eff = __fmul_rn(weight, strength) rounded once. Scan: f32 state,
// unfused mul/add; exact batch mean via ballot/popcount; correctly-rounded
// expf via (float)exp((double)quotient).
//
// R5 = R4 main loop unchanged + coalesced epilogue. R4's per-lane 16-B
// scattered C stores caused 14x write amplification (WRITE 908 MB) and
// RFO/pollution fetch (+255 MB); fix: after the k-loop the A/W LDS is
// dead, overlay a float C[128][128] tile (union), stage tot[][] with a
// rotation swizzle (col' = (col+4*row)&127, <=4-way), then store 512-B
// contiguous per 32-lane half-instruction. Store values bit-identical.

#define KT 32

__device__ __forceinline__ void async_copy16(const float* g, float* l) {
    __builtin_amdgcn_global_load_lds(
        (const __attribute__((address_space(1))) void*)g,
        (__attribute__((address_space(3))) void*)l, 16, 0, 0);
}

// weff[i][hl] = __fmul_rn(weight[i][h_base+hl], strength[i][h_base+hl])
__global__ __launch_bounds__(256) void weff_kernel(
    const float* __restrict__ weight, const float* __restrict__ strength,
    float* __restrict__ weff, int h_base, int Hc)
{
    const int i = blockIdx.x;  // input row 0..2047
    const float* wr = weight   + (size_t)i * 2048 + h_base;
    const float* sr = strength + (size_t)i * 2048 + h_base;
    float* dr = weff + (size_t)i * Hc;
    for (int c = threadIdx.x * 4; c < Hc; c += 1024) {
        float4 wv = *(const float4*)&wr[c];
        float4 sv = *(const float4*)&sr[c];
        float4 o;
        o.x = __fmul_rn(wv.x, sv.x);
        o.y = __fmul_rn(wv.y, sv.y);
        o.z = __fmul_rn(wv.z, sv.z);
        o.w = __fmul_rn(wv.w, sv.w);
        *(float4*)&dr[c] = o;
    }
}

struct __align__(16) SharedMem {
    union {
        struct { float A[2][KT][128]; float W[2][KT][128]; } t;  // 64 KiB
        float C[128][128];                                       // 64 KiB
    };
};

__global__ __launch_bounds__(256, 2) void gemm_kernel(
    const float* __restrict__ spikes,  // [64][2048][128]
    const float* __restrict__ weff,    // [2048][Hc]
    float* __restrict__ Ct,            // [Hc][M=8192]
    int Hc)
{
    __shared__ SharedMem sh;

    const int tid  = threadIdx.x;
    const int w    = tid >> 6;         // wave 0..3 -> m-slice w*32..w*32+31
    const int lane = tid & 63;         // lane -> h pair (2*lane, 2*lane+1)
    const int bx   = blockIdx.x;       // h-tile within chunk
    const int by   = blockIdx.y;       // batch b
    const int h0l  = bx * 128;
    const int m0   = by * 128;

    float acc[32][2];   // current 320-panel accumulator (ascending-k chain)
    float tot[32][2];   // running unfused panel total
#pragma unroll
    for (int i = 0; i < 32; i++) {
        acc[i][0] = 0.0f; acc[i][1] = 0.0f;
        tot[i][0] = 0.0f; tot[i][1] = 0.0f;
    }

    const float* a_base = spikes + (size_t)by * 262144;  // b * I * T

    // Stage tile kt into buffer buf (R1's proven DMA pattern).
    // A tile = rows k0..k0+31 x 128 t = 16 KiB CONTIGUOUS global; wave w
    // covers its 4-KiB quarter with 4 instrs. W tile = 32 rows of 512 B
    // (global stride Hc); 2 rows per instr (lanes 0-31 row r, 32-63 r+1).
    auto stage = [&](int buf, int kt) {
        const int k0 = kt * KT;
        const float* asrc = a_base + ((size_t)k0 << 7) + (w << 10) + (lane << 2);
        float* adst = &sh.t.A[buf][0][0] + (w << 10);
#pragma unroll
        for (int i = 0; i < 4; i++)
            async_copy16(asrc + (i << 8), adst + (i << 8));

        const float* wsrc = &weff[(size_t)(k0 + (w << 3) + (lane >> 5)) * Hc
                                  + h0l + ((lane & 31) << 2)];
        float* wdst = &sh.t.W[buf][w << 3][0];
#pragma unroll
        for (int j = 0; j < 4; j++)
            async_copy16(wsrc + (size_t)(2 * j) * Hc, wdst + (j << 8));
    };

    stage(0, 0);
    __syncthreads();   // prologue drain (only exposed DMA latency)

    int cur = 0;
    for (int kt = 0; kt < 64; kt++) {
        if (kt < 63) stage(cur ^ 1, kt + 1);   // issue DMA, no wait

        // Per k: 8 wave-uniform b128 broadcasts (A, free) + 1 b64 (B,
        // 512 B spread) + 64 v_fmac. All LDS offsets are compile-time
        // immediates off per-buffer bases.
#pragma unroll
        for (int k = 0; k < KT; k++) {
            const float4 a0 = *(const float4*)&sh.t.A[cur][k][(w << 5) + 0];
            const float4 a1 = *(const float4*)&sh.t.A[cur][k][(w << 5) + 4];
            const float4 a2 = *(const float4*)&sh.t.A[cur][k][(w << 5) + 8];
            const float4 a3 = *(const float4*)&sh.t.A[cur][k][(w << 5) + 12];
            const float4 a4 = *(const float4*)&sh.t.A[cur][k][(w << 5) + 16];
            const float4 a5 = *(const float4*)&sh.t.A[cur][k][(w << 5) + 20];
            const float4 a6 = *(const float4*)&sh.t.A[cur][k][(w << 5) + 24];
            const float4 a7 = *(const float4*)&sh.t.A[cur][k][(w << 5) + 28];
            const float2 bv = *(const float2*)&sh.t.W[cur][k][lane << 1];
#define FMA2(mi, av) \
            acc[mi][0] = __builtin_fmaf(av, bv.x, acc[mi][0]); \
            acc[mi][1] = __builtin_fmaf(av, bv.y, acc[mi][1]);
            FMA2(0,  a0.x) FMA2(1,  a0.y) FMA2(2,  a0.z) FMA2(3,  a0.w)
            FMA2(4,  a1.x) FMA2(5,  a1.y) FMA2(6,  a1.z) FMA2(7,  a1.w)
            FMA2(8,  a2.x) FMA2(9,  a2.y) FMA2(10, a2.z) FMA2(11, a2.w)
            FMA2(12, a3.x) FMA2(13, a3.y) FMA2(14, a3.z) FMA2(15, a3.w)
            FMA2(16, a4.x) FMA2(17, a4.y) FMA2(18, a4.z) FMA2(19, a4.w)
            FMA2(20, a5.x) FMA2(21, a5.y) FMA2(22, a5.z) FMA2(23, a5.w)
            FMA2(24, a6.x) FMA2(25, a6.y) FMA2(26, a6.z) FMA2(27, a6.w)
            FMA2(28, a7.x) FMA2(29, a7.y) FMA2(30, a7.z) FMA2(31, a7.w)
#undef FMA2
        }

        // Eigen kc=320 panel boundary: unfused fold into total, reset chain
        if (((kt + 1) % 10 == 0) || (kt == 63)) {
#pragma unroll
            for (int i = 0; i < 32; i++) {
                tot[i][0] = __fadd_rn(tot[i][0], acc[i][0]); acc[i][0] = 0.0f;
                tot[i][1] = __fadd_rn(tot[i][1], acc[i][1]); acc[i][1] = 0.0f;
            }
        }

        __syncthreads();   // implicit vmcnt(0) drain: DMA had full compute
        cur ^= 1;          // phase to land; also fences buffer reuse
    }

    // ---- Coalesced epilogue: transpose via LDS (A/W buffers are dead). ----
    // Write: lane's strip (h-local row = 2*lane+d, m-local cols w*32..+31)
    // with rotation swizzle col' = (col + 4*row) & 127  (<=4-way banks).
#pragma unroll
    for (int d = 0; d < 2; d++) {
        const int row = (lane << 1) + d;
        const int rot = row << 2;
#pragma unroll
        for (int i = 0; i < 8; i++) {
            const int col  = (w << 5) + (i << 2);
            const int colp = (col + rot) & 127;
            *(float4*)&sh.C[row][colp] = make_float4(
                tot[4 * i][d], tot[4 * i + 1][d],
                tot[4 * i + 2][d], tot[4 * i + 3][d]);
        }
    }
    __syncthreads();
    // Read + store: per instruction, each 32-lane half writes one 512-B
    // contiguous, line-aligned segment of a C row (full HBM sectors).
    const int half = lane >> 5;
    const int cl   = (lane & 31) << 2;
#pragma unroll
    for (int rr = 0; rr < 16; rr++) {
        const int row  = (w << 5) + (rr << 1) + half;
        const int colp = (cl + (row << 2)) & 127;
        const float4 v = *(const float4*)&sh.C[row][colp];
        *(float4*)&Ct[(size_t)(h0l + row) * 8192 + m0 + cl] = v;
    }
}

// One wave (64 lanes) per h; lane = batch b. Scan state f32, unfused.
// Batch-mean via ballot/popcount (exact). Validated numerics — UNCHANGED
// (verbatim R1 version; Wt layout [Hc][B][T] = [Hc][8192]).
__global__ __launch_bounds__(256) void scan_kernel(
    const float* __restrict__ Wt,          // [Hc][B][T] f32 chunk-local
    const float* __restrict__ threshold,   // [H] f32 global
    const float* __restrict__ p_tau_mem,
    const float* __restrict__ p_tau_syn,
    const float* __restrict__ p_target,
    const float* __restrict__ p_lr,
    float* __restrict__ out,               // [B][H][T] f32 global
    int h_base)
{
    __shared__ float S[4 * 64 * 17];
    __shared__ unsigned int Bits[4][64][4];

    const int tid  = threadIdx.x;
    const int w    = tid >> 6;
    const int lane = tid & 63;            // batch b
    const int hl   = blockIdx.x * 4 + w;  // chunk-local h

    const float tau_mem = p_tau_mem[0];
    const float tau_syn = p_tau_syn[0];
    const float target  = p_target[0];
    const float lr      = p_lr[0];
    const float a_mem = (float)exp((double)__fdiv_rn(-0.001f, tau_mem));
    const float a_syn = (float)exp((double)__fdiv_rn(-0.001f, tau_syn));

    float i_syn = 0.0f, v_mem = 0.0f;
    float thr = threshold[h_base + hl];
    float fre = 0.0f;
    unsigned int bits[4] = {0u, 0u, 0u, 0u};

    const int st4 = tid & 3;
    const int sb  = (tid >> 2) & 63;

    for (int tc = 0; tc < 128; tc += 16) {
        __syncthreads();
#pragma unroll
        for (int hh = 0; hh < 4; hh++) {
            const int hg = blockIdx.x * 4 + hh;
            float4 v = *(const float4*)&Wt[(size_t)hg * 8192 + sb * 128 + tc + 4 * st4];
            float* row = &S[(hh * 64 + sb) * 17];
            row[4 * st4 + 0] = v.x;
            row[4 * st4 + 1] = v.y;
            row[4 * st4 + 2] = v.z;
            row[4 * st4 + 3] = v.w;
        }
        __syncthreads();

        const float* row = &S[(w * 64 + lane) * 17];
#pragma unroll
        for (int tt = 0; tt < 16; tt++) {
            const int t = tc + tt;
            const float wv = row[tt];
            i_syn = __fadd_rn(__fmul_rn(a_syn, i_syn), wv);
            v_mem = __fadd_rn(__fmul_rn(a_mem, v_mem), i_syn);
            const bool sp = (v_mem >= thr);
            const unsigned long long mask = __ballot(sp);
            if (sp) v_mem = __fsub_rn(v_mem, thr);
            const int cnt = __popcll(mask);
            const float rate = __fmul_rn((float)cnt, 0.015625f);
            fre = __fadd_rn(__fmul_rn(0.99f, fre), __fmul_rn(0.01f, rate));
            thr = __fadd_rn(thr, __fmul_rn(lr, __fsub_rn(fre, target)));
            if (sp) bits[t >> 5] |= (1u << (t & 31));
        }
    }

    __syncthreads();
    Bits[w][lane][0] = bits[0];
    Bits[w][lane][1] = bits[1];
    Bits[w][lane][2] = bits[2];
    Bits[w][lane][3] = bits[3];
    __syncthreads();

    for (int b = 0; b < 64; b++) {
        const unsigned int word = Bits[w][b][lane >> 4];
        float2 v;
        v.x = ((word >> ((2 * lane) & 31)) & 1u) ? 1.0f : 0.0f;
        v.y = ((word >> ((2 * lane + 1) & 31)) & 1u) ? 1.0f : 0.0f;
        *(float2*)&out[((size_t)b * 2048 + h_base + hl) * 128 + 2 * lane] = v;
    }
}

extern "C" void kernel_launch(void* const* d_in, const int* in_sizes, int n_in,
                              void* d_out, int out_size, void* d_ws, size_t ws_size,
                              hipStream_t stream) {
    const float* spikes    = (const float*)d_in[0];
    const float* weight    = (const float*)d_in[1];
    const float* strength  = (const float*)d_in[2];
    const float* threshold = (const float*)d_in[3];
    const float* tau_mem   = (const float*)d_in[4];
    const float* tau_syn   = (const float*)d_in[5];
    const float* target    = (const float*)d_in[6];
    const float* lr        = (const float*)d_in[7];

    float* out = (float*)d_out;

    // ws holds Wt [Hc][8192] f32 + weff [2048][Hc] f32 = Hc*40960 bytes.
    int Hc = 2048;
    while (Hc > 128 && (size_t)Hc * 40960ull > ws_size) Hc >>= 1;

    float* Wt   = (float*)d_ws;
    float* weff = (float*)d_ws + (size_t)Hc * 8192;

    for (int hb = 0; hb < 2048; hb += Hc) {
        weff_kernel<<<2048, 256, 0, stream>>>(weight, strength, weff, hb, Hc);
        gemm_kernel<<<dim3(Hc / 128, 64), 256, 0, stream>>>(spikes, weff, Wt, Hc);
        scan_kernel<<<Hc / 4, 256, 0, stream>>>(
            Wt, threshold, tau_mem, tau_syn, target, lr, out, hb);
    }
}